// Round 8
// baseline (930.028 us; speedup 1.0000x reference)
//
#include <hip/hip_runtime.h>
#include <float.h>
#include <math.h>

// Problem constants (fixed by the reference: N=8192, D=512, k+1=31).
#define NN 8192
#define DD 512
#define TOPK 31
#define CAPR 256          // per-row candidate cap (typical cnt ~70)
#define DELTA1 4.5e-3f    // guaranteed |exact - hi*hi MFMA| bound (~4.0e-3)

// Strategy (R8):
//   Bit-exact value chain (absmax 0.0 since R3):
//     h = relu(f*W1)*W2 ; n = sqrtf(numpy-pairwise sum h*h) ; e = h/n
//     sim[i][j] = sequential-k fmaf chain over e_i*e_j ; stable top-31
//   sim is NEVER materialized. Approx = bf16(hi)-only MFMA GEMM.
//   |exact - approx| <= 2*||lo||*||hi|| + ||lo||^2 + fp32-accum < DELTA1
//   (Cauchy-Schwarz, ||e||=1, |lo_k| <= 2^-9 |e_k|).
//   pass0: upper-tri 128x128 tiles -> per-row tile maxima TM[8192][64].
//   thresh: T = 31st largest TM (sound lower bound on 31st approx value),
//           Tc = T - 2*DELTA1.
//   pass1: identical K-loop (same kernel => identical accs); epilogue pushes
//          candidate col indices with acc >= Tc[row] (+ mirrored test).
//   final: per row, exact fmaf chains for candidates, stable top-31, write
//          zeros + relu(exact). Overflow rows -> flag -> exact cleanup.

typedef __attribute__((ext_vector_type(8))) short short8;
typedef __attribute__((ext_vector_type(4))) float f32x4;

__device__ __forceinline__ float h_elem(const float* __restrict__ f,
                                        const float* __restrict__ W1,
                                        const float* __restrict__ W2, int k) {
  float x = f[k] * W1[k];
  x = fmaxf(x, 0.0f);
  return x * W2[k];
}

__device__ __forceinline__ unsigned short f2bf_rne(float x) {
  unsigned u = __float_as_uint(x);
  unsigned r = (u >> 16) & 1u;
  u += 0x7fffu + r;
  return (unsigned short)(u >> 16);
}
__device__ __forceinline__ unsigned ordmap(float x) {
  unsigned u = __float_as_uint(x);
  return (u & 0x80000000u) ? ~u : (u | 0x80000000u);
}
__device__ __forceinline__ float ordunmap(unsigned u) {
  return __uint_as_float((u & 0x80000000u) ? (u & 0x7fffffffu) : ~u);
}

// ---------------------------------------------------------------------------
// Kernel A: fused norm (numpy pairwise association, bit-exact) + e = h/n,
// bf16 hi split, flag zeroing. One wave per row.
// ---------------------------------------------------------------------------
__global__ __launch_bounds__(256) void emb_kernel(
    const float* __restrict__ f, const float* __restrict__ W1,
    const float* __restrict__ W2, float* __restrict__ e32,
    unsigned short* __restrict__ Ehi, int* __restrict__ flags) {
  const int lane = threadIdx.x & 63;
  const int row = blockIdx.x * 4 + (threadIdx.x >> 6);
  const float* fr = f + (size_t)row * DD;
  const int b = lane >> 4, L = lane & 15;
  if (lane == 0) flags[row] = 0;

  float s[8];
#pragma unroll
  for (int j = 0; j < 8; ++j) {
    float h = h_elem(fr, W1, W2, b * 128 + 16 * j + L);
    s[j] = h * h;
  }
  float v = ((s[0] + s[1]) + (s[2] + s[3])) + ((s[4] + s[5]) + (s[6] + s[7]));
  float t = v + __shfl_xor(v, 8);
  t = t + __shfl_xor(t, 4);
  t = t + __shfl_xor(t, 2);
  float nb = t + __shfl_xor(t, 1);
  float x = nb + __shfl_xor(nb, 16);
  float norm2 = x + __shfl_xor(x, 32);
  const float n = fmaxf(sqrtf(norm2), 1e-12f);

  float* er = e32 + (size_t)row * DD;
  unsigned short* hr = Ehi + (size_t)row * DD;
#pragma unroll
  for (int m = 0; m < 8; ++m) {
    int k = m * 64 + lane;
    float e = h_elem(fr, W1, W2, k) / n;
    er[k] = e;
    hr[k] = f2bf_rne(e);
  }
}

// ---------------------------------------------------------------------------
// Kernel B: hi-only bf16 MFMA GEMM over upper-triangle 128x128 tiles.
// BK=64, 32 MFMAs per barrier pair. Shared by both phases (identical K-loop
// machine code => identical accs => the margin proof holds deterministically).
// phase 0: epilogue reduces per-row (and mirrored per-col) tile maxima -> TM.
// phase 1: epilogue pushes candidate indices where acc >= Tc (+ mirror).
// No sim matrix is ever written.
// ---------------------------------------------------------------------------
#define TSTR 72  // LDS row stride in shorts (frag reads: 2-way conflicts only)

__global__ __launch_bounds__(256) void sim_pass(
    const unsigned short* __restrict__ Ehi, float* __restrict__ TM,
    const float* __restrict__ Tc, int* __restrict__ ccnt,
    int* __restrict__ cidxg, int phase) {
  const int bx = blockIdx.x, by = blockIdx.y;
  if (bx < by) return;

  __shared__ __align__(16) unsigned short As[128 * TSTR];
  __shared__ __align__(16) unsigned short Bs[128 * TSTR];
  __shared__ float Tcr[128], Tcc[128];
  __shared__ float rmx[128][2], cmx[128][2];

  const int t = threadIdx.x;
  const int lane = t & 63, w = t >> 6;
  const int wr = w >> 1, wc = w & 1;
  const int quad = lane >> 4, l16 = lane & 15;
  const int i0 = by * 128, j0 = bx * 128;

  if (phase == 1 && t < 128) {
    Tcr[t] = Tc[i0 + t];
    Tcc[t] = Tc[j0 + t];
  }

  f32x4 acc[4][4];
#pragma unroll
  for (int a = 0; a < 4; ++a)
#pragma unroll
    for (int b = 0; b < 4; ++b) acc[a][b] = (f32x4){0.f, 0.f, 0.f, 0.f};

  const int sr = t >> 1;         // staging row 0..127 (2 threads/row)
  const int c0 = (t & 1) * 32;   // staging k-offset in shorts: 0 or 32
  const size_t ga = (size_t)(i0 + sr) * DD;
  const size_t gb = (size_t)(j0 + sr) * DD;

  for (int kk = 0; kk < DD; kk += 64) {
    __syncthreads();
    uint4 av[4], bv[4];
#pragma unroll
    for (int q = 0; q < 4; ++q) {
      av[q] = *(const uint4*)&Ehi[ga + kk + c0 + q * 8];
      bv[q] = *(const uint4*)&Ehi[gb + kk + c0 + q * 8];
    }
#pragma unroll
    for (int q = 0; q < 4; ++q) {
      *(uint4*)&As[sr * TSTR + c0 + q * 8] = av[q];
      *(uint4*)&Bs[sr * TSTR + c0 + q * 8] = bv[q];
    }
    __syncthreads();
#pragma unroll
    for (int ks = 0; ks < 2; ++ks) {
      short8 af[4], bf[4];
#pragma unroll
      for (int mt = 0; mt < 4; ++mt)
        af[mt] = *(const short8*)&As[(wr * 64 + mt * 16 + l16) * TSTR + ks * 32 + quad * 8];
#pragma unroll
      for (int nt = 0; nt < 4; ++nt)
        bf[nt] = *(const short8*)&Bs[(wc * 64 + nt * 16 + l16) * TSTR + ks * 32 + quad * 8];
#pragma unroll
      for (int mt = 0; mt < 4; ++mt)
#pragma unroll
        for (int nt = 0; nt < 4; ++nt)
          acc[mt][nt] = __builtin_amdgcn_mfma_f32_16x16x32_bf16(
              af[mt], bf[nt], acc[mt][nt], 0, 0, 0);
    }
  }

  if (phase == 0) {
    // per-row tile maxima (C/D layout: col = l16, row = quad*4 + r)
#pragma unroll
    for (int mt = 0; mt < 4; ++mt)
#pragma unroll
      for (int r = 0; r < 4; ++r) {
        float m = fmaxf(fmaxf(acc[mt][0][r], acc[mt][1][r]),
                        fmaxf(acc[mt][2][r], acc[mt][3][r]));
        m = fmaxf(m, __shfl_xor(m, 1));
        m = fmaxf(m, __shfl_xor(m, 2));
        m = fmaxf(m, __shfl_xor(m, 4));
        m = fmaxf(m, __shfl_xor(m, 8));
        if (l16 == 0) rmx[wr * 64 + mt * 16 + quad * 4 + r][wc] = m;
      }
    if (bx > by) {
#pragma unroll
      for (int nt = 0; nt < 4; ++nt) {
        float c = -FLT_MAX;
#pragma unroll
        for (int mt = 0; mt < 4; ++mt)
#pragma unroll
          for (int r = 0; r < 4; ++r) c = fmaxf(c, acc[mt][nt][r]);
        c = fmaxf(c, __shfl_xor(c, 16));
        c = fmaxf(c, __shfl_xor(c, 32));
        if (quad == 0) cmx[wc * 64 + nt * 16 + l16][wr] = c;
      }
    }
    __syncthreads();
    if (t < 128) TM[(size_t)(i0 + t) * 64 + bx] = fmaxf(rmx[t][0], rmx[t][1]);
    if (bx > by && t < 128)
      TM[(size_t)(j0 + t) * 64 + by] = fmaxf(cmx[t][0], cmx[t][1]);
  } else {
    __syncthreads();  // Tcr/Tcc visible
#pragma unroll
    for (int mt = 0; mt < 4; ++mt) {
      const int li = wr * 64 + mt * 16 + quad * 4;  // local row base
#pragma unroll
      for (int nt = 0; nt < 4; ++nt) {
        const int lj = wc * 64 + nt * 16 + l16;     // local col
#pragma unroll
        for (int r = 0; r < 4; ++r) {
          float val = acc[mt][nt][r];
          if (val >= Tcr[li + r]) {
            int gi = i0 + li + r;
            int p = atomicAdd(&ccnt[gi], 1);
            if (p < CAPR) cidxg[(size_t)gi * CAPR + p] = j0 + lj;
          }
          if (bx > by && val >= Tcc[lj]) {
            int gj = j0 + lj;
            int p = atomicAdd(&ccnt[gj], 1);
            if (p < CAPR) cidxg[(size_t)gj * CAPR + p] = i0 + li + r;
          }
        }
      }
    }
  }
}

// ---------------------------------------------------------------------------
// Kernel C: per-row threshold Tc = (31st largest tile-max) - 2*DELTA1,
// and candidate-counter zeroing. One wave per row.
// ---------------------------------------------------------------------------
__global__ __launch_bounds__(256) void thresh_kernel(
    const float* __restrict__ TM, float* __restrict__ Tc,
    int* __restrict__ ccnt) {
  const int lane = threadIdx.x & 63;
  const int row = blockIdx.x * 4 + (threadIdx.x >> 6);
  float mv = TM[(size_t)row * 64 + lane];
  float T = 0.f;
  for (int it = 0; it < TOPK; ++it) {
    unsigned long long key =
        ((unsigned long long)ordmap(mv) << 32) | (unsigned)(63 - lane);
#pragma unroll
    for (int off = 32; off; off >>= 1) {
      unsigned long long o = __shfl_xor(key, off);
      if (o > key) key = o;
    }
    if (it == TOPK - 1) T = ordunmap((unsigned)(key >> 32));
    if (lane == 63 - (int)(key & 63u)) mv = -FLT_MAX;
  }
  if (lane == 0) {
    Tc[row] = T - 2.0f * DELTA1;
    ccnt[row] = 0;
  }
}

// ---------------------------------------------------------------------------
// Kernel D: one WAVE per row. Exact fmaf chains for the listed candidates
// (bit-identical to the verified chain), stable top-31 by (exact desc,
// idx asc), then a single zeros+scatter stream write of the output row.
// ---------------------------------------------------------------------------
__global__ __launch_bounds__(256) void final_kernel(
    float* __restrict__ C, const float* __restrict__ e32,
    const int* __restrict__ ccnt, const int* __restrict__ cidxg,
    int* __restrict__ flags) {
  const int w = threadIdx.x >> 6;
  const int lane = threadIdx.x & 63;
  const int row = blockIdx.x * 4 + w;

  __shared__ float er[4][DD];                      // 8 KB
  __shared__ int cidx[4][CAPR];                    // 4 KB
  __shared__ float cval[4][CAPR];                  // 4 KB
  __shared__ unsigned long long bmap[4][NN / 64];  // 4 KB
  __shared__ int kidx[4][TOPK];
  __shared__ float kval[4][TOPK];

  const int cnt = ccnt[row];
  if (cnt > CAPR) {
    if (lane == 0) flags[row] = 1;
    return;
  }

  {
    const float4* e4 = (const float4*)(e32 + (size_t)row * DD);
    float4* er4 = (float4*)er[w];
    er4[lane] = e4[lane];
    er4[64 + lane] = e4[64 + lane];
  }
  for (int c = lane; c < cnt; c += 64) cidx[w][c] = cidxg[(size_t)row * CAPR + c];
#pragma unroll
  for (int q = 0; q < 2; ++q) bmap[w][q * 64 + lane] = 0ull;

  // exact sequential-k fmaf chains (bit-identical to the verified chain)
  for (int c = lane; c < cnt; c += 64) {
    const float4* ej4 = (const float4*)(e32 + (size_t)cidx[w][c] * DD);
    float a = 0.f;
    for (int k4 = 0; k4 < DD / 4; ++k4) {
      float4 vv = ej4[k4];
      const float* e = &er[w][k4 * 4];
      a = fmaf(e[0], vv.x, a);
      a = fmaf(e[1], vv.y, a);
      a = fmaf(e[2], vv.z, a);
      a = fmaf(e[3], vv.w, a);
    }
    cval[w][c] = a;
  }

  // stable top-31 by (exact desc, idx asc); rank unique => direct slot
  for (int c = lane; c < cnt; c += 64) {
    float v = cval[w][c];
    int idx = cidx[w][c];
    int rank = 0;
    for (int c2 = 0; c2 < cnt; ++c2) {
      float v2 = cval[w][c2];
      if (v2 > v || (v2 == v && cidx[w][c2] < idx)) ++rank;
    }
    if (rank < TOPK) {
      kidx[w][rank] = idx;
      kval[w][rank] = fmaxf(v, 0.0f);  // relu
      atomicOr(&bmap[w][idx >> 6], 1ull << (idx & 63));
    }
  }

  // stream-write the output row (0 or kept value)
  float4* Cw4 = (float4*)(C + (size_t)row * NN);
  for (int it = 0; it < 32; ++it) {
    int j4 = (it * 64 + lane) * 4;
    float4 o = make_float4(0.f, 0.f, 0.f, 0.f);
    unsigned long long word = bmap[w][j4 >> 6];
    unsigned nib = (unsigned)((word >> (j4 & 63)) & 0xFull);
    if (nib) {
#pragma unroll
      for (int c = 0; c < 4; ++c)
        if ((nib >> c) & 1u) {
          int j = j4 + c;
          float val = 0.f;
          for (int s = 0; s < TOPK; ++s)
            if (kidx[w][s] == j) val = kval[w][s];
          ((float*)&o)[c] = val;
        }
    }
    Cw4[it * 64 + lane] = o;
  }
}

// ---------------------------------------------------------------------------
// Kernel E: exact cleanup for flagged rows (statistically never executes).
// ---------------------------------------------------------------------------
__global__ __launch_bounds__(256) void cleanup_kernel(
    float* __restrict__ C, const float* __restrict__ e32,
    const int* __restrict__ flags) {
  const int row = blockIdx.x;
  if (flags[row] == 0) return;
  const int tid = threadIdx.x;
  const int lane = tid & 63, wid = tid >> 6;

  __shared__ float sv[NN];
  __shared__ float er[DD];
  __shared__ unsigned long long wred[4];
  __shared__ int kidx[TOPK];
  __shared__ float kval[TOPK];

  {
    const float4* e4 = (const float4*)(e32 + (size_t)row * DD);
    if (tid < DD / 4) ((float4*)er)[tid] = e4[tid];
  }
  __syncthreads();

  for (int m = 0; m < NN / 256; ++m) {
    int j = m * 256 + tid;
    const float* ej = e32 + (size_t)j * DD;
    float a = 0.f;
    for (int k = 0; k < DD; k += 4) {
      float4 v = *(const float4*)&ej[k];
      a = fmaf(er[k], v.x, a);
      a = fmaf(er[k + 1], v.y, a);
      a = fmaf(er[k + 2], v.z, a);
      a = fmaf(er[k + 3], v.w, a);
    }
    sv[j] = a;
  }
  __syncthreads();

  for (int it = 0; it < TOPK; ++it) {
    float bv = -FLT_MAX;
    int bi = 0;
    for (int j = tid; j < NN; j += 256) {
      float v = sv[j];
      if (v > bv) { bv = v; bi = j; }
    }
    unsigned long long key =
        ((unsigned long long)ordmap(bv) << 32) | (unsigned)(NN - 1 - bi);
#pragma unroll
    for (int off = 32; off; off >>= 1) {
      unsigned long long o = __shfl_xor(key, off);
      if (o > key) key = o;
    }
    if (lane == 0) wred[wid] = key;
    __syncthreads();
    if (tid == 0) {
      unsigned long long k0 = wred[0];
      if (wred[1] > k0) k0 = wred[1];
      if (wred[2] > k0) k0 = wred[2];
      if (wred[3] > k0) k0 = wred[3];
      int idx = (NN - 1) - (int)(k0 & 0xFFFFFFFFu);
      kidx[it] = idx;
      kval[it] = sv[idx];
      sv[idx] = -FLT_MAX;
    }
    __syncthreads();
  }

  float4 z4 = make_float4(0.f, 0.f, 0.f, 0.f);
  float4* sv4 = (float4*)sv;
  for (int i = tid; i < NN / 4; i += 256) sv4[i] = z4;
  __syncthreads();
  if (tid < TOPK) sv[kidx[tid]] = fmaxf(kval[tid], 0.0f);
  __syncthreads();
  float4* Cw4 = (float4*)(C + (size_t)row * NN);
  for (int i = tid; i < NN / 4; i += 256) Cw4[i] = sv4[i];
}

// ---------------------------------------------------------------------------
extern "C" void kernel_launch(void* const* d_in, const int* in_sizes, int n_in,
                              void* d_out, int out_size, void* d_ws,
                              size_t ws_size, hipStream_t stream) {
  const float* f = (const float*)d_in[0];
  const float* W1 = (const float*)d_in[1];
  const float* W2 = (const float*)d_in[2];
  float* out = (float*)d_out;
  char* ws = (char*)d_ws;
  float* e32 = (float*)ws;                                            // 16 MiB
  unsigned short* Ehi = (unsigned short*)(ws + (size_t)NN * DD * 4);  // 8 MiB
  float* TM = (float*)(ws + (size_t)NN * DD * 6);                     // 2 MiB
  float* Tc = (float*)(ws + (size_t)NN * DD * 6 + (size_t)NN * 256);  // 32 KB
  int* ccnt = (int*)((char*)Tc + (size_t)NN * 4);                     // 32 KB
  int* flags = (int*)((char*)ccnt + (size_t)NN * 4);                  // 32 KB
  int* cidxg = (int*)((char*)flags + (size_t)NN * 4);                 // 8 MiB

  emb_kernel<<<NN / 4, 256, 0, stream>>>(f, W1, W2, e32, Ehi, flags);
  dim3 g2(NN / 128, NN / 128);
  sim_pass<<<g2, 256, 0, stream>>>(Ehi, TM, Tc, ccnt, cidxg, 0);
  thresh_kernel<<<NN / 4, 256, 0, stream>>>(TM, Tc, ccnt);
  sim_pass<<<g2, 256, 0, stream>>>(Ehi, TM, Tc, ccnt, cidxg, 1);
  final_kernel<<<NN / 4, 256, 0, stream>>>(out, e32, ccnt, cidxg, flags);
  cleanup_kernel<<<NN, 256, 0, stream>>>(out, e32, flags);
}

// Round 9
// 760.981 us; speedup vs baseline: 1.2221x; 1.2221x over previous
//
#include <hip/hip_runtime.h>
#include <float.h>
#include <math.h>

// Problem constants (fixed by the reference: N=8192, D=512, k+1=31).
#define NN 8192
#define DD 512
#define TOPK 31
#define CAPR 256         // per-row candidate cap (expected cnt ~60)
#define DH 4.5e-3f       // sound |exact-chain - hi*hi| bound (Cauchy-Schwarz)
#define D3 1.0e-4f       // sound |exact-chain - 3-term MFMA| bound

// Strategy (R9):
//   Bit-exact value chain (absmax 0.0 since R3):
//     h = relu(f*W1)*W2 ; n = sqrtf(numpy-pairwise sum h*h) ; e = h/n
//     sim[i][j] = sequential-k fmaf chain over e_i*e_j ; stable top-31
//   sim never materialized. pass0: hi-only bf16 MFMA -> row tile-maxima TM.
//   thresh: Tc = (31st tile-max) - (DH + D3)  [<= E31 - D3, sound coverage].
//   pass1: 3-term MFMA (hi*hi + lo*hi + hi*lo, delta D3); collects
//     (idx, approx) for approx >= Tc (+ mirrored test).
//   final: rank candidates by approx; membership certain outside the
//     boundary band; exact sequential chains ONLY for the band B (rare).
//   Output values = approx (err <= D3 << 2e-2 threshold); SET = exact.
//   GEMM staging: global_load_lds width-16, XOR-swizzled 16B chunks.

typedef __attribute__((ext_vector_type(8))) short short8;
typedef __attribute__((ext_vector_type(4))) float f32x4;

__device__ __forceinline__ float h_elem(const float* __restrict__ f,
                                        const float* __restrict__ W1,
                                        const float* __restrict__ W2, int k) {
  float x = f[k] * W1[k];
  x = fmaxf(x, 0.0f);
  return x * W2[k];
}

__device__ __forceinline__ unsigned short f2bf_rne(float x) {
  unsigned u = __float_as_uint(x);
  unsigned r = (u >> 16) & 1u;
  u += 0x7fffu + r;
  return (unsigned short)(u >> 16);
}
__device__ __forceinline__ float bf2f(unsigned short h) {
  return __uint_as_float(((unsigned)h) << 16);
}
__device__ __forceinline__ unsigned ordmap(float x) {
  unsigned u = __float_as_uint(x);
  return (u & 0x80000000u) ? ~u : (u | 0x80000000u);
}
__device__ __forceinline__ float ordunmap(unsigned u) {
  return __uint_as_float((u & 0x80000000u) ? (u & 0x7fffffffu) : ~u);
}

// async global->LDS, 16 B per lane; lds dest = wave-uniform base + lane*16
__device__ __forceinline__ void gl_lds16(const unsigned short* g,
                                         unsigned short* l) {
  __builtin_amdgcn_global_load_lds(
      (const __attribute__((address_space(1))) unsigned int*)g,
      (__attribute__((address_space(3))) unsigned int*)l, 16, 0, 0);
}

// ---------------------------------------------------------------------------
// Kernel A: fused norm (numpy pairwise association, bit-exact) + e = h/n,
// bf16 hi/lo split, flag zeroing. One wave per row.
// ---------------------------------------------------------------------------
__global__ __launch_bounds__(256) void emb_kernel(
    const float* __restrict__ f, const float* __restrict__ W1,
    const float* __restrict__ W2, float* __restrict__ e32,
    unsigned short* __restrict__ Ehi, unsigned short* __restrict__ Elo,
    int* __restrict__ flags) {
  const int lane = threadIdx.x & 63;
  const int row = blockIdx.x * 4 + (threadIdx.x >> 6);
  const float* fr = f + (size_t)row * DD;
  const int b = lane >> 4, L = lane & 15;
  if (lane == 0) flags[row] = 0;

  float s[8];
#pragma unroll
  for (int j = 0; j < 8; ++j) {
    float h = h_elem(fr, W1, W2, b * 128 + 16 * j + L);
    s[j] = h * h;
  }
  float v = ((s[0] + s[1]) + (s[2] + s[3])) + ((s[4] + s[5]) + (s[6] + s[7]));
  float t = v + __shfl_xor(v, 8);
  t = t + __shfl_xor(t, 4);
  t = t + __shfl_xor(t, 2);
  float nb = t + __shfl_xor(t, 1);
  float x = nb + __shfl_xor(nb, 16);
  float norm2 = x + __shfl_xor(x, 32);
  const float n = fmaxf(sqrtf(norm2), 1e-12f);

  float* er = e32 + (size_t)row * DD;
  unsigned short* hr = Ehi + (size_t)row * DD;
  unsigned short* lr = Elo + (size_t)row * DD;
#pragma unroll
  for (int m = 0; m < 8; ++m) {
    int k = m * 64 + lane;
    float e = h_elem(fr, W1, W2, k) / n;
    er[k] = e;
    unsigned short hb = f2bf_rne(e);
    hr[k] = hb;
    lr[k] = f2bf_rne(e - bf2f(hb));
  }
}

// ---------------------------------------------------------------------------
// Kernel B: pass0 — hi-only bf16 MFMA, upper-tri 128x128 tiles, BK=64,
// global_load_lds staging into XOR-swizzled chunks. Epilogue -> TM.
// LDS chunk map: physical chunk pq holds (row = pq>>3, part = (pq&7)^(row&7)).
// Frag read (row R, logical part lp): offset = R*64 + ((lp^(R&7))*8) shorts.
// ---------------------------------------------------------------------------
__global__ __launch_bounds__(256) void pass0_tm(
    const unsigned short* __restrict__ Ehi, float* __restrict__ TM) {
  const int bx = blockIdx.x, by = blockIdx.y;
  if (bx < by) return;
  __shared__ __align__(16) unsigned short S[2 * 128 * 64];  // 32 KB
  __shared__ float rmx[128][2], cmx[128][2];
  const int t = threadIdx.x;
  const int lane = t & 63, w = t >> 6;
  const int wr = w >> 1, wc = w & 1;
  const int quad = lane >> 4, l16 = lane & 15;
  const int i0 = by * 128, j0 = bx * 128;

  f32x4 acc[4][4];
#pragma unroll
  for (int a = 0; a < 4; ++a)
#pragma unroll
    for (int b = 0; b < 4; ++b) acc[a][b] = (f32x4){0.f, 0.f, 0.f, 0.f};

  int prow[4], ppart[4];
#pragma unroll
  for (int c = 0; c < 4; ++c) {
    int pq = c * 256 + t;
    prow[c] = pq >> 3;
    ppart[c] = (pq & 7) ^ (prow[c] & 7);
  }

  for (int kk = 0; kk < DD; kk += 64) {
    __syncthreads();
#pragma unroll
    for (int c = 0; c < 4; ++c) {
      int pq = c * 256 + t;
      gl_lds16(&Ehi[(size_t)(i0 + prow[c]) * DD + kk + ppart[c] * 8], &S[pq * 8]);
      gl_lds16(&Ehi[(size_t)(j0 + prow[c]) * DD + kk + ppart[c] * 8],
               &S[8192 + pq * 8]);
    }
    __syncthreads();  // compiler emits vmcnt(0) drain before barrier
#pragma unroll
    for (int ks = 0; ks < 2; ++ks) {
      short8 af[4], bf[4];
#pragma unroll
      for (int mt = 0; mt < 4; ++mt) {
        int R = wr * 64 + mt * 16 + l16;
        af[mt] = *(const short8*)&S[R * 64 + (((ks * 4 + quad) ^ (R & 7)) * 8)];
      }
#pragma unroll
      for (int nt = 0; nt < 4; ++nt) {
        int R = wc * 64 + nt * 16 + l16;
        bf[nt] =
            *(const short8*)&S[8192 + R * 64 + (((ks * 4 + quad) ^ (R & 7)) * 8)];
      }
#pragma unroll
      for (int mt = 0; mt < 4; ++mt)
#pragma unroll
        for (int nt = 0; nt < 4; ++nt)
          acc[mt][nt] = __builtin_amdgcn_mfma_f32_16x16x32_bf16(
              af[mt], bf[nt], acc[mt][nt], 0, 0, 0);
    }
  }

  // per-row tile maxima (C/D layout: col = l16, row = quad*4 + r)
#pragma unroll
  for (int mt = 0; mt < 4; ++mt)
#pragma unroll
    for (int r = 0; r < 4; ++r) {
      float m = fmaxf(fmaxf(acc[mt][0][r], acc[mt][1][r]),
                      fmaxf(acc[mt][2][r], acc[mt][3][r]));
      m = fmaxf(m, __shfl_xor(m, 1));
      m = fmaxf(m, __shfl_xor(m, 2));
      m = fmaxf(m, __shfl_xor(m, 4));
      m = fmaxf(m, __shfl_xor(m, 8));
      if (l16 == 0) rmx[wr * 64 + mt * 16 + quad * 4 + r][wc] = m;
    }
  if (bx > by) {
#pragma unroll
    for (int nt = 0; nt < 4; ++nt) {
      float c = -FLT_MAX;
#pragma unroll
      for (int mt = 0; mt < 4; ++mt)
#pragma unroll
        for (int r = 0; r < 4; ++r) c = fmaxf(c, acc[mt][nt][r]);
      c = fmaxf(c, __shfl_xor(c, 16));
      c = fmaxf(c, __shfl_xor(c, 32));
      if (quad == 0) cmx[wc * 64 + nt * 16 + l16][wr] = c;
    }
  }
  __syncthreads();
  if (t < 128) TM[(size_t)(i0 + t) * 64 + bx] = fmaxf(rmx[t][0], rmx[t][1]);
  if (bx > by && t < 128)
    TM[(size_t)(j0 + t) * 64 + by] = fmaxf(cmx[t][0], cmx[t][1]);
}

// ---------------------------------------------------------------------------
// Kernel C: Tc = (31st largest tile-max) - (DH + D3); zero ccnt.
// ---------------------------------------------------------------------------
__global__ __launch_bounds__(256) void thresh_kernel(
    const float* __restrict__ TM, float* __restrict__ Tc,
    int* __restrict__ ccnt) {
  const int lane = threadIdx.x & 63;
  const int row = blockIdx.x * 4 + (threadIdx.x >> 6);
  float mv = TM[(size_t)row * 64 + lane];
  float T = 0.f;
  for (int it = 0; it < TOPK; ++it) {
    unsigned long long key =
        ((unsigned long long)ordmap(mv) << 32) | (unsigned)(63 - lane);
#pragma unroll
    for (int off = 32; off; off >>= 1) {
      unsigned long long o = __shfl_xor(key, off);
      if (o > key) key = o;
    }
    if (it == TOPK - 1) T = ordunmap((unsigned)(key >> 32));
    if (lane == 63 - (int)(key & 63u)) mv = -FLT_MAX;
  }
  if (lane == 0) {
    Tc[row] = T - (DH + D3);
    ccnt[row] = 0;
  }
}

// ---------------------------------------------------------------------------
// Kernel D: pass1 — 3-term bf16 MFMA (ah*bh + al*bh + ah*bl), upper-tri,
// BK=64, global_load_lds staging (4 matrices, 64 KB). Epilogue collects
// (idx, approx value) for approx >= Tc[row], plus mirrored col test.
// ---------------------------------------------------------------------------
__global__ __launch_bounds__(256) void pass1_collect(
    const unsigned short* __restrict__ Ehi,
    const unsigned short* __restrict__ Elo, const float* __restrict__ Tc,
    int* __restrict__ ccnt, int* __restrict__ cidxg,
    float* __restrict__ cvalg) {
  const int bx = blockIdx.x, by = blockIdx.y;
  if (bx < by) return;
  __shared__ __align__(16) unsigned short S[4 * 128 * 64];  // 64 KB
  __shared__ float Tcr[128], Tcc[128];
  const int t = threadIdx.x;
  const int lane = t & 63, w = t >> 6;
  const int wr = w >> 1, wc = w & 1;
  const int quad = lane >> 4, l16 = lane & 15;
  const int i0 = by * 128, j0 = bx * 128;

  if (t < 128) {
    Tcr[t] = Tc[i0 + t];
    Tcc[t] = Tc[j0 + t];
  }

  f32x4 acc[4][4];
#pragma unroll
  for (int a = 0; a < 4; ++a)
#pragma unroll
    for (int b = 0; b < 4; ++b) acc[a][b] = (f32x4){0.f, 0.f, 0.f, 0.f};

  int prow[4], ppart[4];
#pragma unroll
  for (int c = 0; c < 4; ++c) {
    int pq = c * 256 + t;
    prow[c] = pq >> 3;
    ppart[c] = (pq & 7) ^ (prow[c] & 7);
  }

  for (int kk = 0; kk < DD; kk += 64) {
    __syncthreads();
#pragma unroll
    for (int c = 0; c < 4; ++c) {
      int pq = c * 256 + t;
      size_t ga = (size_t)(i0 + prow[c]) * DD + kk + ppart[c] * 8;
      size_t gb = (size_t)(j0 + prow[c]) * DD + kk + ppart[c] * 8;
      gl_lds16(&Ehi[ga], &S[pq * 8]);            // AH
      gl_lds16(&Elo[ga], &S[8192 + pq * 8]);     // AL
      gl_lds16(&Ehi[gb], &S[16384 + pq * 8]);    // BH
      gl_lds16(&Elo[gb], &S[24576 + pq * 8]);    // BL
    }
    __syncthreads();
#pragma unroll
    for (int ks = 0; ks < 2; ++ks) {
      short8 ah[4], al[4], bh[4], bl[4];
#pragma unroll
      for (int mt = 0; mt < 4; ++mt) {
        int R = wr * 64 + mt * 16 + l16;
        int off = R * 64 + (((ks * 4 + quad) ^ (R & 7)) * 8);
        ah[mt] = *(const short8*)&S[off];
        al[mt] = *(const short8*)&S[8192 + off];
      }
#pragma unroll
      for (int nt = 0; nt < 4; ++nt) {
        int R = wc * 64 + nt * 16 + l16;
        int off = R * 64 + (((ks * 4 + quad) ^ (R & 7)) * 8);
        bh[nt] = *(const short8*)&S[16384 + off];
        bl[nt] = *(const short8*)&S[24576 + off];
      }
#pragma unroll
      for (int mt = 0; mt < 4; ++mt)
#pragma unroll
        for (int nt = 0; nt < 4; ++nt)
          acc[mt][nt] = __builtin_amdgcn_mfma_f32_16x16x32_bf16(
              ah[mt], bh[nt], acc[mt][nt], 0, 0, 0);
#pragma unroll
      for (int mt = 0; mt < 4; ++mt)
#pragma unroll
        for (int nt = 0; nt < 4; ++nt)
          acc[mt][nt] = __builtin_amdgcn_mfma_f32_16x16x32_bf16(
              al[mt], bh[nt], acc[mt][nt], 0, 0, 0);
#pragma unroll
      for (int mt = 0; mt < 4; ++mt)
#pragma unroll
        for (int nt = 0; nt < 4; ++nt)
          acc[mt][nt] = __builtin_amdgcn_mfma_f32_16x16x32_bf16(
              ah[mt], bl[nt], acc[mt][nt], 0, 0, 0);
    }
  }

  // collect epilogue
#pragma unroll
  for (int mt = 0; mt < 4; ++mt) {
    const int li = wr * 64 + mt * 16 + quad * 4;
#pragma unroll
    for (int nt = 0; nt < 4; ++nt) {
      const int lj = wc * 64 + nt * 16 + l16;
#pragma unroll
      for (int r = 0; r < 4; ++r) {
        float val = acc[mt][nt][r];
        if (val >= Tcr[li + r]) {
          int gi = i0 + li + r;
          int p = atomicAdd(&ccnt[gi], 1);
          if (p < CAPR) {
            cidxg[(size_t)gi * CAPR + p] = j0 + lj;
            cvalg[(size_t)gi * CAPR + p] = val;
          }
        }
        if (bx > by && val >= Tcc[lj]) {
          int gj = j0 + lj;
          int p = atomicAdd(&ccnt[gj], 1);
          if (p < CAPR) {
            cidxg[(size_t)gj * CAPR + p] = i0 + li + r;
            cvalg[(size_t)gj * CAPR + p] = val;
          }
        }
      }
    }
  }
}

// ---------------------------------------------------------------------------
// Kernel E: one WAVE per row. Rank candidates by (approx desc, idx asc);
// membership certain outside the boundary band; exact sequential chains only
// for the band B (gap <= 2*D3). Stream-write zeros + relu(approx).
// ---------------------------------------------------------------------------
__global__ __launch_bounds__(256) void final_kernel(
    float* __restrict__ C, const float* __restrict__ e32,
    const int* __restrict__ ccnt, const int* __restrict__ cidxg,
    const float* __restrict__ cvalg, int* __restrict__ flags) {
  const int w = threadIdx.x >> 6;
  const int lane = threadIdx.x & 63;
  const int row = blockIdx.x * 4 + w;

  __shared__ int cidx[4][CAPR];                    // 4 KB
  __shared__ float cval[4][CAPR];                  // 4 KB
  __shared__ float cex[4][CAPR];                   // 4 KB (chains, band only)
  __shared__ float er[4][DD];                      // 8 KB
  __shared__ unsigned long long bmap[4][NN / 64];  // 4 KB
  __shared__ int kidx[4][TOPK + 1];
  __shared__ float kval[4][TOPK + 1];
  __shared__ float a31s[4], a32s[4];

  const int cnt = ccnt[row];
  if (cnt > CAPR) {
    if (lane == 0) flags[row] = 1;
    return;
  }

  {
    const float4* e4 = (const float4*)(e32 + (size_t)row * DD);
    float4* er4 = (float4*)er[w];
    er4[lane] = e4[lane];
    er4[64 + lane] = e4[64 + lane];
  }
  for (int c = lane; c < cnt; c += 64) {
    cidx[w][c] = cidxg[(size_t)row * CAPR + c];
    cval[w][c] = cvalg[(size_t)row * CAPR + c];
  }
#pragma unroll
  for (int q = 0; q < 2; ++q) bmap[w][q * 64 + lane] = 0ull;
  if (lane < TOPK) kidx[w][lane] = -1;
  if (lane == 0) {
    a31s[w] = -FLT_MAX;
    a32s[w] = -FLT_MAX;
  }

  // approx ranks (ties -> lower idx); record boundary values
  int myr[4];
#pragma unroll
  for (int s = 0; s < 4; ++s) {
    int c = lane + s * 64;
    myr[s] = 1 << 30;
    if (c < cnt) {
      float v = cval[w][c];
      int idx = cidx[w][c];
      int r = 0;
      for (int c2 = 0; c2 < cnt; ++c2) {
        float v2 = cval[w][c2];
        if (v2 > v || (v2 == v && cidx[w][c2] < idx)) ++r;
      }
      myr[s] = r;
      if (r == 30) a31s[w] = v;
      if (r == 31) a32s[w] = v;
    }
  }
  const float a31v = a31s[w];
  const float a32v = a32s[w];
  const bool need_chain = (a31v - a32v) <= 2.0f * D3;

  if (!need_chain) {
    // set = approx top-31
#pragma unroll
    for (int s = 0; s < 4; ++s) {
      int c = lane + s * 64;
      if (c < cnt && myr[s] < TOPK) {
        int idx = cidx[w][c];
        kidx[w][myr[s]] = idx;
        kval[w][myr[s]] = fmaxf(cval[w][c], 0.0f);
        atomicOr(&bmap[w][idx >> 6], 1ull << (idx & 63));
      }
    }
  } else {
    // m = #sure-in (approx > a31v + 2*D3); band B = |approx - a31v| <= 2*D3
    int m = 0;
    for (int c2 = 0; c2 < cnt; ++c2)
      if (cval[w][c2] > a31v + 2.0f * D3) ++m;
    // exact chains for B (bit-identical to the verified sequential chain)
#pragma unroll
    for (int s = 0; s < 4; ++s) {
      int c = lane + s * 64;
      if (c < cnt && fabsf(cval[w][c] - a31v) <= 2.0f * D3) {
        const float4* ej4 = (const float4*)(e32 + (size_t)cidx[w][c] * DD);
        float a = 0.f;
        for (int k4 = 0; k4 < DD / 4; ++k4) {
          float4 vv = ej4[k4];
          const float* e = &er[w][k4 * 4];
          a = fmaf(e[0], vv.x, a);
          a = fmaf(e[1], vv.y, a);
          a = fmaf(e[2], vv.z, a);
          a = fmaf(e[3], vv.w, a);
        }
        cex[w][c] = a;
      }
    }
    // membership
#pragma unroll
    for (int s = 0; s < 4; ++s) {
      int c = lane + s * 64;
      if (c >= cnt) continue;
      float v = cval[w][c];
      int idx = cidx[w][c];
      int slot = -1;
      if (v > a31v + 2.0f * D3) {
        slot = myr[s];  // sure-in: ranks 0..m-1
      } else if (v >= a31v - 2.0f * D3) {
        float ce = cex[w][c];
        int rb = 0;
        for (int c2 = 0; c2 < cnt; ++c2) {
          if (c2 == c) continue;
          if (fabsf(cval[w][c2] - a31v) <= 2.0f * D3) {
            float ce2 = cex[w][c2];
            if (ce2 > ce || (ce2 == ce && cidx[w][c2] < idx)) ++rb;
          }
        }
        if (rb < TOPK - m) slot = m + rb;
      }
      if (slot >= 0 && slot < TOPK) {
        kidx[w][slot] = idx;
        kval[w][slot] = fmaxf(v, 0.0f);
        atomicOr(&bmap[w][idx >> 6], 1ull << (idx & 63));
      }
    }
  }

  // stream-write the output row (0 or kept value)
  float4* Cw4 = (float4*)(C + (size_t)row * NN);
  for (int it = 0; it < 32; ++it) {
    int j4 = (it * 64 + lane) * 4;
    float4 o = make_float4(0.f, 0.f, 0.f, 0.f);
    unsigned long long word = bmap[w][j4 >> 6];
    unsigned nib = (unsigned)((word >> (j4 & 63)) & 0xFull);
    if (nib) {
#pragma unroll
      for (int c = 0; c < 4; ++c)
        if ((nib >> c) & 1u) {
          int j = j4 + c;
          float val = 0.f;
          for (int s = 0; s < TOPK; ++s)
            if (kidx[w][s] == j) val = kval[w][s];
          ((float*)&o)[c] = val;
        }
    }
    Cw4[it * 64 + lane] = o;
  }
}

// ---------------------------------------------------------------------------
// Kernel F: exact cleanup for flagged rows (statistically never executes).
// ---------------------------------------------------------------------------
__global__ __launch_bounds__(256) void cleanup_kernel(
    float* __restrict__ C, const float* __restrict__ e32,
    const int* __restrict__ flags) {
  const int row = blockIdx.x;
  if (flags[row] == 0) return;
  const int tid = threadIdx.x;
  const int lane = tid & 63, wid = tid >> 6;

  __shared__ float sv[NN];
  __shared__ float er[DD];
  __shared__ unsigned long long wred[4];
  __shared__ int kidx[TOPK];
  __shared__ float kval[TOPK];

  {
    const float4* e4 = (const float4*)(e32 + (size_t)row * DD);
    if (tid < DD / 4) ((float4*)er)[tid] = e4[tid];
  }
  __syncthreads();

  for (int m = 0; m < NN / 256; ++m) {
    int j = m * 256 + tid;
    const float* ej = e32 + (size_t)j * DD;
    float a = 0.f;
    for (int k = 0; k < DD; k += 4) {
      float4 v = *(const float4*)&ej[k];
      a = fmaf(er[k], v.x, a);
      a = fmaf(er[k + 1], v.y, a);
      a = fmaf(er[k + 2], v.z, a);
      a = fmaf(er[k + 3], v.w, a);
    }
    sv[j] = a;
  }
  __syncthreads();

  for (int it = 0; it < TOPK; ++it) {
    float bv = -FLT_MAX;
    int bi = 0;
    for (int j = tid; j < NN; j += 256) {
      float v = sv[j];
      if (v > bv) { bv = v; bi = j; }
    }
    unsigned long long key =
        ((unsigned long long)ordmap(bv) << 32) | (unsigned)(NN - 1 - bi);
#pragma unroll
    for (int off = 32; off; off >>= 1) {
      unsigned long long o = __shfl_xor(key, off);
      if (o > key) key = o;
    }
    if (lane == 0) wred[wid] = key;
    __syncthreads();
    if (tid == 0) {
      unsigned long long k0 = wred[0];
      if (wred[1] > k0) k0 = wred[1];
      if (wred[2] > k0) k0 = wred[2];
      if (wred[3] > k0) k0 = wred[3];
      int idx = (NN - 1) - (int)(k0 & 0xFFFFFFFFu);
      kidx[it] = idx;
      kval[it] = sv[idx];
      sv[idx] = -FLT_MAX;
    }
    __syncthreads();
  }

  float4 z4 = make_float4(0.f, 0.f, 0.f, 0.f);
  float4* sv4 = (float4*)sv;
  for (int i = tid; i < NN / 4; i += 256) sv4[i] = z4;
  __syncthreads();
  if (tid < TOPK) sv[kidx[tid]] = fmaxf(kval[tid], 0.0f);
  __syncthreads();
  float4* Cw4 = (float4*)(C + (size_t)row * NN);
  for (int i = tid; i < NN / 4; i += 256) Cw4[i] = sv4[i];
}

// ---------------------------------------------------------------------------
extern "C" void kernel_launch(void* const* d_in, const int* in_sizes, int n_in,
                              void* d_out, int out_size, void* d_ws,
                              size_t ws_size, hipStream_t stream) {
  const float* f = (const float*)d_in[0];
  const float* W1 = (const float*)d_in[1];
  const float* W2 = (const float*)d_in[2];
  float* out = (float*)d_out;
  char* ws = (char*)d_ws;
  float* e32 = (float*)ws;                                             // 16 MiB
  unsigned short* Ehi = (unsigned short*)(ws + (size_t)NN * DD * 4);   // 8 MiB
  unsigned short* Elo = (unsigned short*)(ws + (size_t)NN * DD * 6);   // 8 MiB
  float* TM = (float*)(ws + (size_t)NN * DD * 8);                      // 2 MiB
  char* p = ws + (size_t)NN * DD * 8 + (size_t)NN * 64 * 4;
  float* Tc = (float*)p;                                               // 32 KB
  int* ccnt = (int*)(p + (size_t)NN * 4);                              // 32 KB
  int* flags = (int*)(p + (size_t)NN * 8);                             // 32 KB
  int* cidxg = (int*)(p + (size_t)NN * 12);                            // 8 MiB
  float* cvalg = (float*)(p + (size_t)NN * 12 + (size_t)NN * CAPR * 4);// 8 MiB

  emb_kernel<<<NN / 4, 256, 0, stream>>>(f, W1, W2, e32, Ehi, Elo, flags);
  dim3 g2(NN / 128, NN / 128);
  pass0_tm<<<g2, 256, 0, stream>>>(Ehi, TM);
  thresh_kernel<<<NN / 4, 256, 0, stream>>>(TM, Tc, ccnt);
  pass1_collect<<<g2, 256, 0, stream>>>(Ehi, Elo, Tc, ccnt, cidxg, cvalg);
  final_kernel<<<NN / 4, 256, 0, stream>>>(out, e32, ccnt, cidxg, cvalg, flags);
  cleanup_kernel<<<NN, 256, 0, stream>>>(out, e32, flags);
}

// Round 10
// 730.436 us; speedup vs baseline: 1.2733x; 1.0418x over previous
//
#include <hip/hip_runtime.h>
#include <float.h>
#include <math.h>

// Problem constants (fixed by the reference: N=8192, D=512, k+1=31).
#define NN 8192
#define DD 512
#define TOPK 31
#define CAPR 256         // per-row candidate cap (expected cnt ~60)
#define DH 4.5e-3f       // sound |exact-chain - hi*hi| bound (Cauchy-Schwarz)
#define D3 1.0e-4f       // sound |exact-chain - 3-term MFMA| bound
#define NTILE 64         // 8192/128
#define NTRI (NTILE * (NTILE + 1) / 2)  // 2080 upper-tri tiles

// Strategy (R10 = R9 + occupancy fix):
//   Bit-exact value chain (absmax 0.0 R3..R8):
//     h = relu(f*W1)*W2 ; n = sqrtf(numpy-pairwise sum h*h) ; e = h/n
//     sim[i][j] = sequential-k fmaf chain ; stable top-31 (ties -> lower idx)
//   sim never materialized. pass0: hi-only bf16 MFMA -> row tile-maxima TM.
//   thresh: Tc = (31st tile-max) - (DH + D3)   [<= E31 - D3, sound coverage]
//   pass1: 3-term MFMA (hh + lh + hl); collects (idx, approx) >= Tc (+mirror).
//   final: rank by approx; exact chains only for the boundary band (2*D3).
//   R10: BK=32 (pass1 LDS 64->32 KB => 4 blocks/CU), triangular 1-D grid
//   (no dead blocks), 4-part XOR swizzle (2-way LDS conflicts = free).

typedef __attribute__((ext_vector_type(8))) short short8;
typedef __attribute__((ext_vector_type(4))) float f32x4;

__device__ __forceinline__ float h_elem(const float* __restrict__ f,
                                        const float* __restrict__ W1,
                                        const float* __restrict__ W2, int k) {
  float x = f[k] * W1[k];
  x = fmaxf(x, 0.0f);
  return x * W2[k];
}

__device__ __forceinline__ unsigned short f2bf_rne(float x) {
  unsigned u = __float_as_uint(x);
  unsigned r = (u >> 16) & 1u;
  u += 0x7fffu + r;
  return (unsigned short)(u >> 16);
}
__device__ __forceinline__ float bf2f(unsigned short h) {
  return __uint_as_float(((unsigned)h) << 16);
}
__device__ __forceinline__ unsigned ordmap(float x) {
  unsigned u = __float_as_uint(x);
  return (u & 0x80000000u) ? ~u : (u | 0x80000000u);
}
__device__ __forceinline__ float ordunmap(unsigned u) {
  return __uint_as_float((u & 0x80000000u) ? (u & 0x7fffffffu) : ~u);
}

// async global->LDS, 16 B/lane; LDS dest = wave-uniform base + lane*16
__device__ __forceinline__ void gl_lds16(const unsigned short* g,
                                         unsigned short* l) {
  __builtin_amdgcn_global_load_lds(
      (const __attribute__((address_space(1))) unsigned int*)g,
      (__attribute__((address_space(3))) unsigned int*)l, 16, 0, 0);
}

// triangular decode: block s -> (bx >= by)
__device__ __forceinline__ void tri_decode(int s, int& bx, int& by) {
  int b = 0;
  while (s >= NTILE - b) {
    s -= NTILE - b;
    ++b;
  }
  by = b;
  bx = b + s;
}

// ---------------------------------------------------------------------------
// Kernel A: fused norm (numpy pairwise association, bit-exact) + e = h/n,
// bf16 hi/lo split, flag zeroing. One wave per row.
// ---------------------------------------------------------------------------
__global__ __launch_bounds__(256) void emb_kernel(
    const float* __restrict__ f, const float* __restrict__ W1,
    const float* __restrict__ W2, float* __restrict__ e32,
    unsigned short* __restrict__ Ehi, unsigned short* __restrict__ Elo,
    int* __restrict__ flags) {
  const int lane = threadIdx.x & 63;
  const int row = blockIdx.x * 4 + (threadIdx.x >> 6);
  const float* fr = f + (size_t)row * DD;
  const int b = lane >> 4, L = lane & 15;
  if (lane == 0) flags[row] = 0;

  float s[8];
#pragma unroll
  for (int j = 0; j < 8; ++j) {
    float h = h_elem(fr, W1, W2, b * 128 + 16 * j + L);
    s[j] = h * h;
  }
  float v = ((s[0] + s[1]) + (s[2] + s[3])) + ((s[4] + s[5]) + (s[6] + s[7]));
  float t = v + __shfl_xor(v, 8);
  t = t + __shfl_xor(t, 4);
  t = t + __shfl_xor(t, 2);
  float nb = t + __shfl_xor(t, 1);
  float x = nb + __shfl_xor(nb, 16);
  float norm2 = x + __shfl_xor(x, 32);
  const float n = fmaxf(sqrtf(norm2), 1e-12f);

  float* er = e32 + (size_t)row * DD;
  unsigned short* hr = Ehi + (size_t)row * DD;
  unsigned short* lr = Elo + (size_t)row * DD;
#pragma unroll
  for (int m = 0; m < 8; ++m) {
    int k = m * 64 + lane;
    float e = h_elem(fr, W1, W2, k) / n;
    er[k] = e;
    unsigned short hb = f2bf_rne(e);
    hr[k] = hb;
    lr[k] = f2bf_rne(e - bf2f(hb));
  }
}

// ---------------------------------------------------------------------------
// Kernel B: pass0 — hi-only bf16 MFMA, triangular grid, BK=32, 16 KB LDS.
// LDS chunk map (per matrix, 512 chunks of 16 B): pq -> row = pq>>2,
// phys part = (pq&3); holds global logical part lp = (pq&3)^(row&3).
// Frag read (row R, logical part q=quad): shorts offset R*32 + ((q^(R&3))*8).
// ---------------------------------------------------------------------------
__global__ __launch_bounds__(256) void pass0_tm(
    const unsigned short* __restrict__ Ehi, float* __restrict__ TM) {
  int bx, by;
  tri_decode(blockIdx.x, bx, by);
  __shared__ __align__(16) unsigned short S[2 * 128 * 32];  // 16 KB
  __shared__ float rmx[128][2], cmx[128][2];
  const int t = threadIdx.x;
  const int lane = t & 63, w = t >> 6;
  const int wr = w >> 1, wc = w & 1;
  const int quad = lane >> 4, l16 = lane & 15;
  const int i0 = by * 128, j0 = bx * 128;

  f32x4 acc[4][4];
#pragma unroll
  for (int a = 0; a < 4; ++a)
#pragma unroll
    for (int b = 0; b < 4; ++b) acc[a][b] = (f32x4){0.f, 0.f, 0.f, 0.f};

  int prow[2], plp[2];
#pragma unroll
  for (int c = 0; c < 2; ++c) {
    int pq = c * 256 + t;
    prow[c] = pq >> 2;
    plp[c] = (pq & 3) ^ (prow[c] & 3);
  }

  for (int kk = 0; kk < DD; kk += 32) {
    __syncthreads();
#pragma unroll
    for (int c = 0; c < 2; ++c) {
      int pq = c * 256 + t;
      gl_lds16(&Ehi[(size_t)(i0 + prow[c]) * DD + kk + plp[c] * 8], &S[pq * 8]);
      gl_lds16(&Ehi[(size_t)(j0 + prow[c]) * DD + kk + plp[c] * 8],
               &S[4096 + pq * 8]);
    }
    __syncthreads();
    short8 af[4], bf[4];
#pragma unroll
    for (int mt = 0; mt < 4; ++mt) {
      int R = wr * 64 + mt * 16 + l16;
      af[mt] = *(const short8*)&S[R * 32 + ((quad ^ (R & 3)) * 8)];
    }
#pragma unroll
    for (int nt = 0; nt < 4; ++nt) {
      int R = wc * 64 + nt * 16 + l16;
      bf[nt] = *(const short8*)&S[4096 + R * 32 + ((quad ^ (R & 3)) * 8)];
    }
#pragma unroll
    for (int mt = 0; mt < 4; ++mt)
#pragma unroll
      for (int nt = 0; nt < 4; ++nt)
        acc[mt][nt] = __builtin_amdgcn_mfma_f32_16x16x32_bf16(
            af[mt], bf[nt], acc[mt][nt], 0, 0, 0);
  }

  // per-row tile maxima (C/D layout: col = l16, row = quad*4 + r)
#pragma unroll
  for (int mt = 0; mt < 4; ++mt)
#pragma unroll
    for (int r = 0; r < 4; ++r) {
      float m = fmaxf(fmaxf(acc[mt][0][r], acc[mt][1][r]),
                      fmaxf(acc[mt][2][r], acc[mt][3][r]));
      m = fmaxf(m, __shfl_xor(m, 1));
      m = fmaxf(m, __shfl_xor(m, 2));
      m = fmaxf(m, __shfl_xor(m, 4));
      m = fmaxf(m, __shfl_xor(m, 8));
      if (l16 == 0) rmx[wr * 64 + mt * 16 + quad * 4 + r][wc] = m;
    }
  if (bx > by) {
#pragma unroll
    for (int nt = 0; nt < 4; ++nt) {
      float c = -FLT_MAX;
#pragma unroll
      for (int mt = 0; mt < 4; ++mt)
#pragma unroll
        for (int r = 0; r < 4; ++r) c = fmaxf(c, acc[mt][nt][r]);
      c = fmaxf(c, __shfl_xor(c, 16));
      c = fmaxf(c, __shfl_xor(c, 32));
      if (quad == 0) cmx[wc * 64 + nt * 16 + l16][wr] = c;
    }
  }
  __syncthreads();
  if (t < 128) TM[(size_t)(i0 + t) * 64 + bx] = fmaxf(rmx[t][0], rmx[t][1]);
  if (bx > by && t < 128)
    TM[(size_t)(j0 + t) * 64 + by] = fmaxf(cmx[t][0], cmx[t][1]);
}

// ---------------------------------------------------------------------------
// Kernel C: Tc = (31st largest tile-max) - (DH + D3); zero ccnt.
// ---------------------------------------------------------------------------
__global__ __launch_bounds__(256) void thresh_kernel(
    const float* __restrict__ TM, float* __restrict__ Tc,
    int* __restrict__ ccnt) {
  const int lane = threadIdx.x & 63;
  const int row = blockIdx.x * 4 + (threadIdx.x >> 6);
  float mv = TM[(size_t)row * 64 + lane];
  float T = 0.f;
  for (int it = 0; it < TOPK; ++it) {
    unsigned long long key =
        ((unsigned long long)ordmap(mv) << 32) | (unsigned)(63 - lane);
#pragma unroll
    for (int off = 32; off; off >>= 1) {
      unsigned long long o = __shfl_xor(key, off);
      if (o > key) key = o;
    }
    if (it == TOPK - 1) T = ordunmap((unsigned)(key >> 32));
    if (lane == 63 - (int)(key & 63u)) mv = -FLT_MAX;
  }
  if (lane == 0) {
    Tc[row] = T - (DH + D3);
    ccnt[row] = 0;
  }
}

// ---------------------------------------------------------------------------
// Kernel D: pass1 — 3-term bf16 MFMA (hh + lh + hl), triangular grid, BK=32,
// 32 KB LDS (AH/AL/BH/BL). Epilogue collects (idx, approx) >= Tc (+mirror).
// ---------------------------------------------------------------------------
__global__ __launch_bounds__(256) void pass1_collect(
    const unsigned short* __restrict__ Ehi,
    const unsigned short* __restrict__ Elo, const float* __restrict__ Tc,
    int* __restrict__ ccnt, int* __restrict__ cidxg,
    float* __restrict__ cvalg) {
  int bx, by;
  tri_decode(blockIdx.x, bx, by);
  __shared__ __align__(16) unsigned short S[4 * 128 * 32];  // 32 KB
  __shared__ float Tcr[128], Tcc[128];
  const int t = threadIdx.x;
  const int lane = t & 63, w = t >> 6;
  const int wr = w >> 1, wc = w & 1;
  const int quad = lane >> 4, l16 = lane & 15;
  const int i0 = by * 128, j0 = bx * 128;

  if (t < 128) {
    Tcr[t] = Tc[i0 + t];
    Tcc[t] = Tc[j0 + t];
  }

  f32x4 acc[4][4];
#pragma unroll
  for (int a = 0; a < 4; ++a)
#pragma unroll
    for (int b = 0; b < 4; ++b) acc[a][b] = (f32x4){0.f, 0.f, 0.f, 0.f};

  int prow[2], plp[2];
#pragma unroll
  for (int c = 0; c < 2; ++c) {
    int pq = c * 256 + t;
    prow[c] = pq >> 2;
    plp[c] = (pq & 3) ^ (prow[c] & 3);
  }

  for (int kk = 0; kk < DD; kk += 32) {
    __syncthreads();
#pragma unroll
    for (int c = 0; c < 2; ++c) {
      int pq = c * 256 + t;
      size_t ga = (size_t)(i0 + prow[c]) * DD + kk + plp[c] * 8;
      size_t gb = (size_t)(j0 + prow[c]) * DD + kk + plp[c] * 8;
      gl_lds16(&Ehi[ga], &S[pq * 8]);           // AH
      gl_lds16(&Elo[ga], &S[4096 + pq * 8]);    // AL
      gl_lds16(&Ehi[gb], &S[8192 + pq * 8]);    // BH
      gl_lds16(&Elo[gb], &S[12288 + pq * 8]);   // BL
    }
    __syncthreads();
    short8 ah[4], al[4], bh[4], bl[4];
#pragma unroll
    for (int mt = 0; mt < 4; ++mt) {
      int R = wr * 64 + mt * 16 + l16;
      int off = R * 32 + ((quad ^ (R & 3)) * 8);
      ah[mt] = *(const short8*)&S[off];
      al[mt] = *(const short8*)&S[4096 + off];
    }
#pragma unroll
    for (int nt = 0; nt < 4; ++nt) {
      int R = wc * 64 + nt * 16 + l16;
      int off = R * 32 + ((quad ^ (R & 3)) * 8);
      bh[nt] = *(const short8*)&S[8192 + off];
      bl[nt] = *(const short8*)&S[12288 + off];
    }
#pragma unroll
    for (int mt = 0; mt < 4; ++mt)
#pragma unroll
      for (int nt = 0; nt < 4; ++nt)
        acc[mt][nt] = __builtin_amdgcn_mfma_f32_16x16x32_bf16(
            ah[mt], bh[nt], acc[mt][nt], 0, 0, 0);
#pragma unroll
    for (int mt = 0; mt < 4; ++mt)
#pragma unroll
      for (int nt = 0; nt < 4; ++nt)
        acc[mt][nt] = __builtin_amdgcn_mfma_f32_16x16x32_bf16(
            al[mt], bh[nt], acc[mt][nt], 0, 0, 0);
#pragma unroll
    for (int mt = 0; mt < 4; ++mt)
#pragma unroll
      for (int nt = 0; nt < 4; ++nt)
        acc[mt][nt] = __builtin_amdgcn_mfma_f32_16x16x32_bf16(
            ah[mt], bl[nt], acc[mt][nt], 0, 0, 0);
  }

  // collect epilogue
#pragma unroll
  for (int mt = 0; mt < 4; ++mt) {
    const int li = wr * 64 + mt * 16 + quad * 4;
#pragma unroll
    for (int nt = 0; nt < 4; ++nt) {
      const int lj = wc * 64 + nt * 16 + l16;
#pragma unroll
      for (int r = 0; r < 4; ++r) {
        float val = acc[mt][nt][r];
        if (val >= Tcr[li + r]) {
          int gi = i0 + li + r;
          int p = atomicAdd(&ccnt[gi], 1);
          if (p < CAPR) {
            cidxg[(size_t)gi * CAPR + p] = j0 + lj;
            cvalg[(size_t)gi * CAPR + p] = val;
          }
        }
        if (bx > by && val >= Tcc[lj]) {
          int gj = j0 + lj;
          int p = atomicAdd(&ccnt[gj], 1);
          if (p < CAPR) {
            cidxg[(size_t)gj * CAPR + p] = i0 + li + r;
            cvalg[(size_t)gj * CAPR + p] = val;
          }
        }
      }
    }
  }
}

// ---------------------------------------------------------------------------
// Kernel E: one WAVE per row. Rank candidates by (approx desc, idx asc);
// membership certain outside the boundary band; exact sequential chains only
// for the band B (gap <= 2*D3). Stream-write zeros + relu(approx).
// ---------------------------------------------------------------------------
__global__ __launch_bounds__(256) void final_kernel(
    float* __restrict__ C, const float* __restrict__ e32,
    const int* __restrict__ ccnt, const int* __restrict__ cidxg,
    const float* __restrict__ cvalg, int* __restrict__ flags) {
  const int w = threadIdx.x >> 6;
  const int lane = threadIdx.x & 63;
  const int row = blockIdx.x * 4 + w;

  __shared__ int cidx[4][CAPR];
  __shared__ float cval[4][CAPR];
  __shared__ float cex[4][CAPR];
  __shared__ float er[4][DD];
  __shared__ unsigned long long bmap[4][NN / 64];
  __shared__ int kidx[4][TOPK + 1];
  __shared__ float kval[4][TOPK + 1];
  __shared__ float a31s[4], a32s[4];

  const int cnt = ccnt[row];
  if (cnt > CAPR) {
    if (lane == 0) flags[row] = 1;
    return;
  }

  {
    const float4* e4 = (const float4*)(e32 + (size_t)row * DD);
    float4* er4 = (float4*)er[w];
    er4[lane] = e4[lane];
    er4[64 + lane] = e4[64 + lane];
  }
  for (int c = lane; c < cnt; c += 64) {
    cidx[w][c] = cidxg[(size_t)row * CAPR + c];
    cval[w][c] = cvalg[(size_t)row * CAPR + c];
  }
#pragma unroll
  for (int q = 0; q < 2; ++q) bmap[w][q * 64 + lane] = 0ull;
  if (lane < TOPK) kidx[w][lane] = -1;
  if (lane == 0) {
    a31s[w] = -FLT_MAX;
    a32s[w] = -FLT_MAX;
  }

  // approx ranks (ties -> lower idx); record boundary values
  int myr[4];
#pragma unroll
  for (int s = 0; s < 4; ++s) {
    int c = lane + s * 64;
    myr[s] = 1 << 30;
    if (c < cnt) {
      float v = cval[w][c];
      int idx = cidx[w][c];
      int r = 0;
      for (int c2 = 0; c2 < cnt; ++c2) {
        float v2 = cval[w][c2];
        if (v2 > v || (v2 == v && cidx[w][c2] < idx)) ++r;
      }
      myr[s] = r;
      if (r == 30) a31s[w] = v;
      if (r == 31) a32s[w] = v;
    }
  }
  const float a31v = a31s[w];
  const float a32v = a32s[w];
  const bool need_chain = (a31v - a32v) <= 2.0f * D3;

  if (!need_chain) {
#pragma unroll
    for (int s = 0; s < 4; ++s) {
      int c = lane + s * 64;
      if (c < cnt && myr[s] < TOPK) {
        int idx = cidx[w][c];
        kidx[w][myr[s]] = idx;
        kval[w][myr[s]] = fmaxf(cval[w][c], 0.0f);
        atomicOr(&bmap[w][idx >> 6], 1ull << (idx & 63));
      }
    }
  } else {
    int m = 0;
    for (int c2 = 0; c2 < cnt; ++c2)
      if (cval[w][c2] > a31v + 2.0f * D3) ++m;
    // exact chains for the band (bit-identical to the verified chain)
#pragma unroll
    for (int s = 0; s < 4; ++s) {
      int c = lane + s * 64;
      if (c < cnt && fabsf(cval[w][c] - a31v) <= 2.0f * D3) {
        const float4* ej4 = (const float4*)(e32 + (size_t)cidx[w][c] * DD);
        float a = 0.f;
        for (int k4 = 0; k4 < DD / 4; ++k4) {
          float4 vv = ej4[k4];
          const float* e = &er[w][k4 * 4];
          a = fmaf(e[0], vv.x, a);
          a = fmaf(e[1], vv.y, a);
          a = fmaf(e[2], vv.z, a);
          a = fmaf(e[3], vv.w, a);
        }
        cex[w][c] = a;
      }
    }
#pragma unroll
    for (int s = 0; s < 4; ++s) {
      int c = lane + s * 64;
      if (c >= cnt) continue;
      float v = cval[w][c];
      int idx = cidx[w][c];
      int slot = -1;
      if (v > a31v + 2.0f * D3) {
        slot = myr[s];
      } else if (v >= a31v - 2.0f * D3) {
        float ce = cex[w][c];
        int rb = 0;
        for (int c2 = 0; c2 < cnt; ++c2) {
          if (c2 == c) continue;
          if (fabsf(cval[w][c2] - a31v) <= 2.0f * D3) {
            float ce2 = cex[w][c2];
            if (ce2 > ce || (ce2 == ce && cidx[w][c2] < idx)) ++rb;
          }
        }
        if (rb < TOPK - m) slot = m + rb;
      }
      if (slot >= 0 && slot < TOPK) {
        kidx[w][slot] = idx;
        kval[w][slot] = fmaxf(v, 0.0f);
        atomicOr(&bmap[w][idx >> 6], 1ull << (idx & 63));
      }
    }
  }

  // stream-write the output row (0 or kept value)
  float4* Cw4 = (float4*)(C + (size_t)row * NN);
  for (int it = 0; it < 32; ++it) {
    int j4 = (it * 64 + lane) * 4;
    float4 o = make_float4(0.f, 0.f, 0.f, 0.f);
    unsigned long long word = bmap[w][j4 >> 6];
    unsigned nib = (unsigned)((word >> (j4 & 63)) & 0xFull);
    if (nib) {
#pragma unroll
      for (int c = 0; c < 4; ++c)
        if ((nib >> c) & 1u) {
          int j = j4 + c;
          float val = 0.f;
          for (int s = 0; s < TOPK; ++s)
            if (kidx[w][s] == j) val = kval[w][s];
          ((float*)&o)[c] = val;
        }
    }
    Cw4[it * 64 + lane] = o;
  }
}

// ---------------------------------------------------------------------------
// Kernel F: exact cleanup for flagged rows (statistically never executes).
// ---------------------------------------------------------------------------
__global__ __launch_bounds__(256) void cleanup_kernel(
    float* __restrict__ C, const float* __restrict__ e32,
    const int* __restrict__ flags) {
  const int row = blockIdx.x;
  if (flags[row] == 0) return;
  const int tid = threadIdx.x;
  const int lane = tid & 63, wid = tid >> 6;

  __shared__ float sv[NN];
  __shared__ float er[DD];
  __shared__ unsigned long long wred[4];
  __shared__ int kidx[TOPK];
  __shared__ float kval[TOPK];

  {
    const float4* e4 = (const float4*)(e32 + (size_t)row * DD);
    if (tid < DD / 4) ((float4*)er)[tid] = e4[tid];
  }
  __syncthreads();

  for (int m = 0; m < NN / 256; ++m) {
    int j = m * 256 + tid;
    const float* ej = e32 + (size_t)j * DD;
    float a = 0.f;
    for (int k = 0; k < DD; k += 4) {
      float4 v = *(const float4*)&ej[k];
      a = fmaf(er[k], v.x, a);
      a = fmaf(er[k + 1], v.y, a);
      a = fmaf(er[k + 2], v.z, a);
      a = fmaf(er[k + 3], v.w, a);
    }
    sv[j] = a;
  }
  __syncthreads();

  for (int it = 0; it < TOPK; ++it) {
    float bv = -FLT_MAX;
    int bi = 0;
    for (int j = tid; j < NN; j += 256) {
      float v = sv[j];
      if (v > bv) { bv = v; bi = j; }
    }
    unsigned long long key =
        ((unsigned long long)ordmap(bv) << 32) | (unsigned)(NN - 1 - bi);
#pragma unroll
    for (int off = 32; off; off >>= 1) {
      unsigned long long o = __shfl_xor(key, off);
      if (o > key) key = o;
    }
    if (lane == 0) wred[wid] = key;
    __syncthreads();
    if (tid == 0) {
      unsigned long long k0 = wred[0];
      if (wred[1] > k0) k0 = wred[1];
      if (wred[2] > k0) k0 = wred[2];
      if (wred[3] > k0) k0 = wred[3];
      int idx = (NN - 1) - (int)(k0 & 0xFFFFFFFFu);
      kidx[it] = idx;
      kval[it] = sv[idx];
      sv[idx] = -FLT_MAX;
    }
    __syncthreads();
  }

  float4 z4 = make_float4(0.f, 0.f, 0.f, 0.f);
  float4* sv4 = (float4*)sv;
  for (int i = tid; i < NN / 4; i += 256) sv4[i] = z4;
  __syncthreads();
  if (tid < TOPK) sv[kidx[tid]] = fmaxf(kval[tid], 0.0f);
  __syncthreads();
  float4* Cw4 = (float4*)(C + (size_t)row * NN);
  for (int i = tid; i < NN / 4; i += 256) Cw4[i] = sv4[i];
}

// ---------------------------------------------------------------------------
extern "C" void kernel_launch(void* const* d_in, const int* in_sizes, int n_in,
                              void* d_out, int out_size, void* d_ws,
                              size_t ws_size, hipStream_t stream) {
  const float* f = (const float*)d_in[0];
  const float* W1 = (const float*)d_in[1];
  const float* W2 = (const float*)d_in[2];
  float* out = (float*)d_out;
  char* ws = (char*)d_ws;
  float* e32 = (float*)ws;                                             // 16 MiB
  unsigned short* Ehi = (unsigned short*)(ws + (size_t)NN * DD * 4);   // 8 MiB
  unsigned short* Elo = (unsigned short*)(ws + (size_t)NN * DD * 6);   // 8 MiB
  float* TM = (float*)(ws + (size_t)NN * DD * 8);                      // 2 MiB
  char* p = ws + (size_t)NN * DD * 8 + (size_t)NN * 64 * 4;
  float* Tc = (float*)p;                                               // 32 KB
  int* ccnt = (int*)(p + (size_t)NN * 4);                              // 32 KB
  int* flags = (int*)(p + (size_t)NN * 8);                             // 32 KB
  int* cidxg = (int*)(p + (size_t)NN * 12);                            // 8 MiB
  float* cvalg = (float*)(p + (size_t)NN * 12 + (size_t)NN * CAPR * 4);// 8 MiB

  emb_kernel<<<NN / 4, 256, 0, stream>>>(f, W1, W2, e32, Ehi, Elo, flags);
  pass0_tm<<<NTRI, 256, 0, stream>>>(Ehi, TM);
  thresh_kernel<<<NN / 4, 256, 0, stream>>>(TM, Tc, ccnt);
  pass1_collect<<<NTRI, 256, 0, stream>>>(Ehi, Elo, Tc, ccnt, cidxg, cvalg);
  final_kernel<<<NN / 4, 256, 0, stream>>>(out, e32, ccnt, cidxg, cvalg, flags);
  cleanup_kernel<<<NN, 256, 0, stream>>>(out, e32, flags);
}